// Round 3
// baseline (145.331 us; speedup 1.0000x reference)
//
#include <hip/hip_runtime.h>
#include <hip/hip_cooperative_groups.h>
#include <math.h>

namespace cg = cooperative_groups;

#define NB 16
#define HH 256
#define WW 256
#define NC 128
#define KTOP 8
#define RAD 5
#define TCAP 125
#define TILE_ROWS 16
#define HALO 5
#define LROWS (TILE_ROWS + 2*HALO)   // 26
#define CMAX 2048                    // >= 16*TCAP = 2000

// ---------------- workspace layout (bytes) ----------------
// 0      : float tv[16][16][TCAP]
// 128000 : int   ti[16][16][TCAP]
// 256000 : int   tcount[16][16]
// 257024 : float gpart[16][16]
// 258048 : float pr[16][8]
// 258560 : float pc[16][8]
// 259072 : float pw[16][8]
// 259584 : float wmmax[16]

struct Phase1Mem { float t[LROWS][WW]; float hx[LROWS][WW]; };   // 53248 B
struct Phase2Mem { float cv[CMAX]; int ci[CMAX]; };              // 16384 B
union SMem { Phase1Mem p1; Phase2Mem p2; };

__device__ __forceinline__ float wm_at(int pix, const float* qr, const float* qc, const float* qw) {
    float fi = (float)(pix >> 8);
    float fj = (float)(pix & 255);
    float wmv = 0.f;
#pragma unroll
    for (int k = 0; k < KTOP; ++k) {
        float dr = fi - qr[k];
        float dc = fj - qc[k];
        wmv += qw[k] * __expf(-(dr * dr + dc * dc) * 0.02f);
    }
    return wmv;
}

__global__ void __launch_bounds__(256, 1)
fused(const float* __restrict__ hm, const float* __restrict__ fmap,
      float* __restrict__ out, char* __restrict__ ws) {
    float* tv     = (float*)(ws + 0);
    int*   ti     = (int*)  (ws + 128000);
    int*   tcount = (int*)  (ws + 256000);
    float* gpart  = (float*)(ws + 257024);
    float* pr     = (float*)(ws + 258048);
    float* pc     = (float*)(ws + 258560);
    float* pw     = (float*)(ws + 259072);
    float* wmmax  = (float*)(ws + 259584);

    float* out_rw    = out;                    // 16*256*256
    float* out_feats = out + 1048576;          // 16*8*128
    float* out_pos   = out + 1048576 + 16384;  // 16*8*2
    float* out_probs = out_pos + 256;          // 16*8
    float* out_valid = out_probs + 128;        // 16*8

    __shared__ SMem sm;
    __shared__ float red[256];
    __shared__ int   redi[256];
    __shared__ int   cnt;
    __shared__ int   sct[16];
    __shared__ float s_r[KTOP], s_c[KTOP], s_w[KTOP];
    __shared__ float sel_v[KTOP]; __shared__ int sel_i[KTOP]; __shared__ int sel_p[KTOP];
    __shared__ float qinv;

    int blk = blockIdx.x, tid = threadIdx.x;
    cg::grid_group grid = cg::this_grid();

    // ================= Phase 1: per-tile separable 11x11 NMS =================
    {
        int b    = blk >> 4;
        int tile = blk & 15;
        int row0 = tile * TILE_ROWS;
        int tile_id = blk;
        if (tid == 0) cnt = 0;

        const float4* p4 = (const float4*)(hm + (size_t)b * HH * WW);
        float4 nf = make_float4(-INFINITY, -INFINITY, -INFINITY, -INFINITY);
        for (int i = tid; i < LROWS * (WW / 4); i += 256) {
            int lr = i >> 6, c4 = i & 63;
            int gr = row0 - HALO + lr;
            float4 v = (gr >= 0 && gr < HH) ? p4[gr * 64 + c4] : nf;
            ((float4*)&sm.p1.t[lr][0])[c4] = v;
        }
        __syncthreads();

        for (int i = tid; i < LROWS * WW; i += 256) {
            int lr = i >> 8, col = i & 255;
            int c0 = col - RAD < 0 ? 0 : col - RAD;
            int c1 = col + RAD > WW - 1 ? WW - 1 : col + RAD;
            float m = -INFINITY;
            for (int c = c0; c <= c1; ++c) m = fmaxf(m, sm.p1.t[lr][c]);
            sm.p1.hx[lr][col] = m;
        }
        __syncthreads();

        float tmax = -INFINITY;
        for (int i = tid; i < TILE_ROWS * WW; i += 256) {
            int lr = (i >> 8) + HALO, col = i & 255;
            float v = sm.p1.t[lr][col];
            tmax = fmaxf(tmax, v);
            float m = -INFINITY;
            for (int r = lr - RAD; r <= lr + RAD; ++r) m = fmaxf(m, sm.p1.hx[r][col]);
            if (v >= m) {
                int pos = atomicAdd(&cnt, 1);
                if (pos < TCAP) {
                    tv[tile_id * TCAP + pos] = v;
                    ti[tile_id * TCAP + pos] = (row0 + lr - HALO) * WW + col;
                }
            }
        }
        red[tid] = tmax;
        __syncthreads();
        for (int s = 128; s > 0; s >>= 1) {
            if (tid < s) red[tid] = fmaxf(red[tid], red[tid + s]);
            __syncthreads();
        }
        if (tid == 0) {
            gpart[tile_id]  = red[0];
            tcount[tile_id] = cnt > TCAP ? TCAP : cnt;
        }
    }

    __threadfence();
    grid.sync();

    // ================= Phase 2: select (blocks 0..15, one per batch) =================
    if (blk < NB) {
        int b = blk;
        if (tid == 0) {
            cnt = 0;
            float g = -INFINITY;
            for (int j = 0; j < 16; ++j) g = fmaxf(g, gpart[b * 16 + j]);
            red[0] = 0.05f * g;
        }
        if (tid < 16) sct[tid] = tcount[b * 16 + tid];
        __syncthreads();
        float thresh = red[0];

        for (int i = tid; i < 16 * TCAP; i += 256) {
            int j = i / TCAP, p = i - j * TCAP;
            if (p < sct[j]) {
                float v = tv[(b * 16 + j) * TCAP + p];
                if (v >= thresh) {
                    int pos = atomicAdd(&cnt, 1);
                    sm.p2.cv[pos] = v;
                    sm.p2.ci[pos] = ti[(b * 16 + j) * TCAP + p];
                }
            }
        }
        __syncthreads();
        int count = cnt;

        for (int k = 0; k < KTOP; ++k) {
            float bv = -INFINITY; int bi = 0x7fffffff; int bp = -1;
            for (int i = tid; i < count; i += 256) {
                float v = sm.p2.cv[i]; int idx = sm.p2.ci[i];
                if (v > bv || (v == bv && idx < bi)) { bv = v; bi = idx; bp = i; }
            }
            for (int s = 1; s < 64; s <<= 1) {
                float v = __shfl_xor(bv, s); int idx = __shfl_xor(bi, s); int p = __shfl_xor(bp, s);
                if (v > bv || (v == bv && idx < bi)) { bv = v; bi = idx; bp = p; }
            }
            if ((tid & 63) == 0) { int w = tid >> 6; red[w] = bv; redi[w] = bi; redi[64 + w] = bp; }
            __syncthreads();
            if (tid == 0) {
                float v0 = red[0]; int i0 = redi[0]; int p0 = redi[64];
                for (int j = 1; j < 4; ++j)
                    if (red[j] > v0 || (red[j] == v0 && redi[j] < i0)) {
                        v0 = red[j]; i0 = redi[j]; p0 = redi[64 + j];
                    }
                sel_v[k] = v0; sel_i[k] = i0; sel_p[k] = p0;
                if (p0 >= 0) sm.p2.cv[p0] = -INFINITY;
            }
            __syncthreads();
        }

        if (tid == 0) {
            int next = 0;
            for (int k = 0; k < KTOP; ++k) {
                if (sel_p[k] < 0) {
                    for (;;) {
                        bool taken = false;
                        for (int j = 0; j < count; ++j) if (sm.p2.ci[j] == next) { taken = true; break; }
                        if (!taken) break;
                        ++next;
                    }
                    sel_i[k] = next;
                    sel_v[k] = -1.0e9f;
                    ++next;
                }
            }
            float m = sel_v[0];
            for (int k = 1; k < KTOP; ++k) m = fmaxf(m, sel_v[k]);
            float e[KTOP], s = 0.f;
            for (int k = 0; k < KTOP; ++k) { e[k] = expf(sel_v[k] - m); s += e[k]; }
            for (int k = 0; k < KTOP; ++k) {
                float prob = e[k] / s;
                int idx = sel_i[k];
                float rrow = (float)(idx / WW);
                float rcol = (float)(idx % WW);
                float vld  = sel_v[k] > -1.0e8f ? 1.f : 0.f;
                out_pos[(b * KTOP + k) * 2 + 0] = rrow;
                out_pos[(b * KTOP + k) * 2 + 1] = rcol;
                out_probs[b * KTOP + k] = prob;
                out_valid[b * KTOP + k] = vld;
                pr[b * KTOP + k] = rrow;
                pc[b * KTOP + k] = rcol;
                pw[b * KTOP + k] = prob * vld;
                s_r[k] = rrow; s_c[k] = rcol; s_w[k] = prob * vld;
            }
        }
        __syncthreads();

        // weight-map max: argmax provably within radius 11 of some center
        float m = 0.f;
        for (int i = tid; i < KTOP * 529; i += 256) {
            int k = i / 529, o = i - k * 529;
            int rr = (int)s_r[k] + (o / 23) - 11;
            int cc = (int)s_c[k] + (o % 23) - 11;
            if (rr >= 0 && rr < HH && cc >= 0 && cc < WW)
                m = fmaxf(m, wm_at(rr * WW + cc, s_r, s_c, s_w));
        }
        red[tid] = m;
        __syncthreads();
        for (int s = 128; s > 0; s >>= 1) {
            if (tid < s) red[tid] = fmaxf(red[tid], red[tid + s]);
            __syncthreads();
        }
        if (tid == 0) wmmax[b] = red[0];
    }

    __threadfence();
    grid.sync();

    // ================= Phase 3: feature gather + reweight =================
    {
        // single-tap feature gather (positions are exactly integral)
        int gtid = blk * 256 + tid;
        if (gtid < NB * KTOP * NC) {
            int b  = gtid >> 10;          // 8*128 = 1024 per batch
            int t  = gtid & 1023;
            int k  = t >> 7, ch = t & 127;
            int r = (int)pr[b * KTOP + k];
            int c = (int)pc[b * KTOP + k];
            out_feats[gtid] = fmap[((size_t)b * NC + ch) * HH * WW + r * WW + c];
        }

        int b3 = blk >> 4, tile3 = blk & 15;
        __shared__ float qr[KTOP], qc[KTOP], qw[KTOP];
        if (tid < KTOP) {
            qr[tid] = pr[b3 * KTOP + tid];
            qc[tid] = pc[b3 * KTOP + tid];
            qw[tid] = pw[b3 * KTOP + tid];
        }
        if (tid == 0) qinv = 0.5f / (wmmax[b3] + 1e-8f);
        __syncthreads();
        float inv = qinv;

        const float4* h4 = (const float4*)(hm + (size_t)b3 * HH * WW);
        float4*       o4 = (float4*)(out_rw + (size_t)b3 * HH * WW);
        for (int u = 0; u < 4; ++u) {
            int idx4 = tile3 * 1024 + u * 256 + tid;
            float4 h = h4[idx4];
            int pix = idx4 * 4;
            float4 o;
            o.x = h.x * (0.5f + wm_at(pix + 0, qr, qc, qw) * inv);
            o.y = h.y * (0.5f + wm_at(pix + 1, qr, qc, qw) * inv);
            o.z = h.z * (0.5f + wm_at(pix + 2, qr, qc, qw) * inv);
            o.w = h.w * (0.5f + wm_at(pix + 3, qr, qc, qw) * inv);
            o4[idx4] = o;
        }
    }
}

extern "C" void kernel_launch(void* const* d_in, const int* in_sizes, int n_in,
                              void* d_out, int out_size, void* d_ws, size_t ws_size,
                              hipStream_t stream) {
    const float* heatmap = (const float*)d_in[0];
    const float* fmap    = (const float*)d_in[1];
    float* out = (float*)d_out;
    char*  ws  = (char*)d_ws;

    void* args[] = { (void*)&heatmap, (void*)&fmap, (void*)&out, (void*)&ws };
    hipLaunchCooperativeKernel((const void*)fused, dim3(NB * 16), dim3(256), args, 0, stream);
}

// Round 4
// 60.540 us; speedup vs baseline: 2.4006x; 2.4006x over previous
//
#include <hip/hip_runtime.h>
#include <math.h>

#define NB 16
#define HH 256
#define WW 256
#define NC 128
#define KTOP 8
#define RAD 5
#define TCAP 125
#define TILE_ROWS 16
#define HALO 5
#define LROWS (TILE_ROWS + 2*HALO)   // 26

// ---------------- workspace layout (bytes), total ~260 KB ----------------
// 0      : float tv[16][16][TCAP]
// 128000 : int   ti[16][16][TCAP]
// 256000 : int   tcount[16][16]
// 257024 : float gpart[16][16]
// 258048 : float pr[16][8]
// 258560 : float pc[16][8]
// 259072 : float pw[16][8]
// 259584 : float winv[16]          (0.5 / (wmmax + 1e-8))

// ---------- K1: separable 11x11 NMS, per-tile candidates + per-tile max ----------
__global__ void k_nms(const float* __restrict__ hm,
                      float* __restrict__ gpart, int* __restrict__ tcount,
                      float* __restrict__ tv, int* __restrict__ ti) {
    int b    = blockIdx.x >> 4;
    int tile = blockIdx.x & 15;
    int row0 = tile * TILE_ROWS;
    int tid  = threadIdx.x;

    __shared__ float t[LROWS][WW];
    __shared__ float hx[LROWS][WW];
    __shared__ int   cnt;
    __shared__ float red[256];
    if (tid == 0) cnt = 0;

    const float4* p4 = (const float4*)(hm + (size_t)b * HH * WW);
    float4 nf = make_float4(-INFINITY, -INFINITY, -INFINITY, -INFINITY);
    for (int i = tid; i < LROWS * (WW / 4); i += 256) {
        int lr = i >> 6, c4 = i & 63;
        int gr = row0 - HALO + lr;
        float4 v = (gr >= 0 && gr < HH) ? p4[gr * 64 + c4] : nf;
        ((float4*)&t[lr][0])[c4] = v;
    }
    __syncthreads();

    for (int i = tid; i < LROWS * WW; i += 256) {
        int lr = i >> 8, col = i & 255;
        int c0 = col - RAD < 0 ? 0 : col - RAD;
        int c1 = col + RAD > WW - 1 ? WW - 1 : col + RAD;
        float m = -INFINITY;
        for (int c = c0; c <= c1; ++c) m = fmaxf(m, t[lr][c]);
        hx[lr][col] = m;
    }
    __syncthreads();

    float tmax = -INFINITY;
    int tile_id = blockIdx.x;
    for (int i = tid; i < TILE_ROWS * WW; i += 256) {
        int lr = (i >> 8) + HALO, col = i & 255;
        float v = t[lr][col];
        tmax = fmaxf(tmax, v);
        float m = -INFINITY;
        for (int r = lr - RAD; r <= lr + RAD; ++r) m = fmaxf(m, hx[r][col]);
        if (v >= m) {
            int pos = atomicAdd(&cnt, 1);
            if (pos < TCAP) {
                tv[tile_id * TCAP + pos] = v;
                ti[tile_id * TCAP + pos] = (row0 + lr - HALO) * WW + col;
            }
        }
    }
    red[tid] = tmax;
    __syncthreads();
    for (int s = 128; s > 0; s >>= 1) {
        if (tid < s) red[tid] = fmaxf(red[tid], red[tid + s]);
        __syncthreads();
    }
    if (tid == 0) {
        gpart[tile_id]  = red[0];
        tcount[tile_id] = cnt > TCAP ? TCAP : cnt;
    }
}

__device__ __forceinline__ float wm_at_f(float fi, float fj,
                                         const float* qr, const float* qc, const float* qw) {
    float wmv = 0.f;
#pragma unroll
    for (int k = 0; k < KTOP; ++k) {
        float dr = fi - qr[k];
        float dc = fj - qc[k];
        wmv += qw[k] * __expf(-(dr * dr + dc * dc) * 0.02f);
    }
    return wmv;
}

// ---------- K2: gmax + threshold + top-8 + softmax + analytic wmmax + feature gather ----------
__global__ void k_select(const float* __restrict__ fmap,
                         const float* __restrict__ gpart, const int* __restrict__ tcount,
                         const float* __restrict__ tv, const int* __restrict__ ti,
                         float* __restrict__ out_feats, float* __restrict__ out_pos,
                         float* __restrict__ out_probs, float* __restrict__ out_valid,
                         float* __restrict__ pr, float* __restrict__ pc, float* __restrict__ pw,
                         float* __restrict__ winv) {
    int b = blockIdx.x, tid = threadIdx.x;

    __shared__ float cv[16 * TCAP];
    __shared__ int   ci[16 * TCAP];
    __shared__ int   cnt;
    __shared__ int   sct[16];
    __shared__ float red[256];
    __shared__ int   redi[128];
    __shared__ float sel_v[KTOP]; __shared__ int sel_i[KTOP]; __shared__ int sel_p[KTOP];
    __shared__ float s_r[KTOP], s_c[KTOP], s_w[KTOP];

    if (tid == 0) {
        cnt = 0;
        float g = -INFINITY;
        for (int j = 0; j < 16; ++j) g = fmaxf(g, gpart[b * 16 + j]);
        red[0] = 0.05f * g;
    }
    if (tid < 16) sct[tid] = tcount[b * 16 + tid];
    __syncthreads();
    float thresh = red[0];

    for (int i = tid; i < 16 * TCAP; i += 256) {
        int j = i / TCAP, p = i - j * TCAP;
        if (p < sct[j]) {
            float v = tv[(b * 16 + j) * TCAP + p];
            if (v >= thresh) {
                int pos = atomicAdd(&cnt, 1);
                cv[pos] = v;
                ci[pos] = ti[(b * 16 + j) * TCAP + p];
            }
        }
    }
    __syncthreads();
    int count = cnt;

    for (int k = 0; k < KTOP; ++k) {
        float bv = -INFINITY; int bi = 0x7fffffff; int bp = -1;
        for (int i = tid; i < count; i += 256) {
            float v = cv[i]; int idx = ci[i];
            if (v > bv || (v == bv && idx < bi)) { bv = v; bi = idx; bp = i; }
        }
        for (int s = 1; s < 64; s <<= 1) {
            float v = __shfl_xor(bv, s); int idx = __shfl_xor(bi, s); int p = __shfl_xor(bp, s);
            if (v > bv || (v == bv && idx < bi)) { bv = v; bi = idx; bp = p; }
        }
        if ((tid & 63) == 0) { int w = tid >> 6; red[w] = bv; redi[w] = bi; redi[64 + w] = bp; }
        __syncthreads();
        if (tid == 0) {
            float v0 = red[0]; int i0 = redi[0]; int p0 = redi[64];
            for (int j = 1; j < 4; ++j)
                if (red[j] > v0 || (red[j] == v0 && redi[j] < i0)) {
                    v0 = red[j]; i0 = redi[j]; p0 = redi[64 + j];
                }
            sel_v[k] = v0; sel_i[k] = i0; sel_p[k] = p0;
            if (p0 >= 0) cv[p0] = -INFINITY;
        }
        __syncthreads();
    }

    if (tid == 0) {
        int next = 0;
        for (int k = 0; k < KTOP; ++k) {
            if (sel_p[k] < 0) {
                for (;;) {
                    bool taken = false;
                    for (int j = 0; j < count; ++j) if (ci[j] == next) { taken = true; break; }
                    if (!taken) break;
                    ++next;
                }
                sel_i[k] = next;
                sel_v[k] = -1.0e9f;
                ++next;
            }
        }
        float m = sel_v[0];
        for (int k = 1; k < KTOP; ++k) m = fmaxf(m, sel_v[k]);
        float e[KTOP], s = 0.f;
        for (int k = 0; k < KTOP; ++k) { e[k] = expf(sel_v[k] - m); s += e[k]; }
        for (int k = 0; k < KTOP; ++k) {
            float prob = e[k] / s;
            int idx = sel_i[k];
            float rrow = (float)(idx / WW);
            float rcol = (float)(idx % WW);
            float vld  = sel_v[k] > -1.0e8f ? 1.f : 0.f;
            out_pos[(b * KTOP + k) * 2 + 0] = rrow;
            out_pos[(b * KTOP + k) * 2 + 1] = rcol;
            out_probs[b * KTOP + k] = prob;
            out_valid[b * KTOP + k] = vld;
            pr[b * KTOP + k] = rrow;
            pc[b * KTOP + k] = rcol;
            pw[b * KTOP + k] = prob * vld;
            s_r[k] = rrow; s_c[k] = rcol; s_w[k] = prob * vld;
        }
    }
    __syncthreads();

    // analytic weight-map max: argmax provably within radius 11 of some center
    float m = 0.f;
    for (int i = tid; i < KTOP * 529; i += 256) {
        int k = i / 529, o = i - k * 529;
        int rr = (int)s_r[k] + (o / 23) - 11;
        int cc = (int)s_c[k] + (o % 23) - 11;
        if (rr >= 0 && rr < HH && cc >= 0 && cc < WW)
            m = fmaxf(m, wm_at_f((float)rr, (float)cc, s_r, s_c, s_w));
    }
    red[tid] = m;
    __syncthreads();
    for (int s = 128; s > 0; s >>= 1) {
        if (tid < s) red[tid] = fmaxf(red[tid], red[tid + s]);
        __syncthreads();
    }
    if (tid == 0) winv[b] = 0.5f / (red[0] + 1e-8f);

    // single-tap feature gather (positions are exactly integral)
    for (int t = tid; t < KTOP * NC; t += 256) {
        int k  = t >> 7;
        int ch = t & 127;
        int r = (int)s_r[k];
        int c = (int)s_c[k];
        out_feats[(size_t)b * KTOP * NC + t] = fmap[((size_t)b * NC + ch) * HH * WW + r * WW + c];
    }
}

// ---------- K3: reweight via separable gaussians (8 FMA / pixel) ----------
__global__ void k_reweight(const float* __restrict__ hm,
                           const float* __restrict__ pr, const float* __restrict__ pc,
                           const float* __restrict__ pw, const float* __restrict__ winv,
                           float* __restrict__ out) {
    int tile = blockIdx.x, b = blockIdx.y, tid = threadIdx.x;
    int row0 = tile * TILE_ROWS;

    __shared__ float fc[KTOP][WW];        // col factors
    __shared__ float ar[KTOP][TILE_ROWS]; // weight-folded row factors
    __shared__ float qr[KTOP], qc[KTOP], qw[KTOP];
    __shared__ float qinv;

    if (tid < KTOP) {
        qr[tid] = pr[b * KTOP + tid];
        qc[tid] = pc[b * KTOP + tid];
        qw[tid] = pw[b * KTOP + tid];
    }
    if (tid == 0) qinv = winv[b];
    __syncthreads();

    for (int i = tid; i < KTOP * WW; i += 256) {
        int k = i >> 8, col = i & 255;
        float d = (float)col - qc[k];
        fc[k][col] = __expf(-d * d * 0.02f);
    }
    if (tid < KTOP * TILE_ROWS) {
        int k = tid >> 4, r = tid & 15;
        float d = (float)(row0 + r) - qr[k];
        ar[k][r] = qw[k] * __expf(-d * d * 0.02f);
    }
    __syncthreads();
    float inv = qinv;

    // each thread: one row (r = tid>>4), 16 contiguous px (4 float4)
    int r  = tid >> 4;
    int cb = (tid & 15) * 4;              // float4 col-block base
    float a[KTOP];
#pragma unroll
    for (int k = 0; k < KTOP; ++k) a[k] = ar[k][r];

    const float4* h4 = (const float4*)(hm + (size_t)b * HH * WW + (size_t)(row0 + r) * WW);
    float4*       o4 = (float4*)(out + (size_t)b * HH * WW + (size_t)(row0 + r) * WW);
#pragma unroll
    for (int u = 0; u < 4; ++u) {
        int c4 = cb + u;
        float4 h = h4[c4];
        float4 w = make_float4(0.f, 0.f, 0.f, 0.f);
#pragma unroll
        for (int k = 0; k < KTOP; ++k) {
            float4 f = ((const float4*)&fc[k][0])[c4];
            w.x += a[k] * f.x;
            w.y += a[k] * f.y;
            w.z += a[k] * f.z;
            w.w += a[k] * f.w;
        }
        float4 o;
        o.x = h.x * (0.5f + w.x * inv);
        o.y = h.y * (0.5f + w.y * inv);
        o.z = h.z * (0.5f + w.z * inv);
        o.w = h.w * (0.5f + w.w * inv);
        o4[c4] = o;
    }
}

extern "C" void kernel_launch(void* const* d_in, const int* in_sizes, int n_in,
                              void* d_out, int out_size, void* d_ws, size_t ws_size,
                              hipStream_t stream) {
    const float* heatmap = (const float*)d_in[0];
    const float* fmap    = (const float*)d_in[1];

    float* out = (float*)d_out;
    float* out_reweighted = out;                       // 16*1*256*256 = 1048576
    float* out_feats      = out + 1048576;             // 16*8*128     = 16384
    float* out_pos        = out + 1048576 + 16384;     // 16*8*2       = 256
    float* out_probs      = out_pos + 256;             // 16*8         = 128
    float* out_valid      = out_probs + 128;           // 16*8         = 128

    char* ws = (char*)d_ws;
    float* tv     = (float*)(ws + 0);
    int*   ti     = (int*)  (ws + 128000);
    int*   tcount = (int*)  (ws + 256000);
    float* gpart  = (float*)(ws + 257024);
    float* pr     = (float*)(ws + 258048);
    float* pc     = (float*)(ws + 258560);
    float* pw     = (float*)(ws + 259072);
    float* winv   = (float*)(ws + 259584);

    k_nms<<<NB * 16, 256, 0, stream>>>(heatmap, gpart, tcount, tv, ti);
    k_select<<<NB, 256, 0, stream>>>(fmap, gpart, tcount, tv, ti,
                                     out_feats, out_pos, out_probs, out_valid,
                                     pr, pc, pw, winv);
    k_reweight<<<dim3(16, NB), 256, 0, stream>>>(heatmap, pr, pc, pw, winv, out_reweighted);
}

// Round 5
// 60.174 us; speedup vs baseline: 2.4152x; 1.0061x over previous
//
#include <hip/hip_runtime.h>
#include <math.h>

#define NB 16
#define HH 256
#define WW 256
#define NC 128
#define KTOP 8
#define RAD 5
#define TCAP 128
#define TILE_ROWS 16
#define HALO 5
#define LROWS (TILE_ROWS + 2*HALO)   // 26
#define NT 16                        // tiles per batch
#define CTOT (NT * TCAP)             // 2048

// ---------------- workspace layout (bytes), total ~330 KB ----------------
// 0      : float tv[16][16][TCAP]   (16*16*128*4 = 131072)
// 131072 : int   ti[16][16][TCAP]   (131072)
// 262144 : int   tcount[16][16]     (1024)
// 263168 : float gpart[16][16]      (1024)

// ---------- K1: separable 11x11 NMS, per-tile candidates + per-tile max ----------
__global__ void k_nms(const float* __restrict__ hm,
                      float* __restrict__ gpart, int* __restrict__ tcount,
                      float* __restrict__ tv, int* __restrict__ ti) {
    int b    = blockIdx.x >> 4;
    int tile = blockIdx.x & 15;
    int row0 = tile * TILE_ROWS;
    int tid  = threadIdx.x;

    __shared__ float t[LROWS][WW];
    __shared__ float hx[LROWS][WW];
    __shared__ int   cnt;
    __shared__ float red[256];
    if (tid == 0) cnt = 0;

    const float4* p4 = (const float4*)(hm + (size_t)b * HH * WW);
    float4 nf = make_float4(-INFINITY, -INFINITY, -INFINITY, -INFINITY);
    for (int i = tid; i < LROWS * (WW / 4); i += 256) {
        int lr = i >> 6, c4 = i & 63;
        int gr = row0 - HALO + lr;
        float4 v = (gr >= 0 && gr < HH) ? p4[gr * 64 + c4] : nf;
        ((float4*)&t[lr][0])[c4] = v;
    }
    __syncthreads();

    for (int i = tid; i < LROWS * WW; i += 256) {
        int lr = i >> 8, col = i & 255;
        int c0 = col - RAD < 0 ? 0 : col - RAD;
        int c1 = col + RAD > WW - 1 ? WW - 1 : col + RAD;
        float m = -INFINITY;
        for (int c = c0; c <= c1; ++c) m = fmaxf(m, t[lr][c]);
        hx[lr][col] = m;
    }
    __syncthreads();

    float tmax = -INFINITY;
    int tile_id = blockIdx.x;
    for (int i = tid; i < TILE_ROWS * WW; i += 256) {
        int lr = (i >> 8) + HALO, col = i & 255;
        float v = t[lr][col];
        tmax = fmaxf(tmax, v);
        float m = -INFINITY;
        for (int r = lr - RAD; r <= lr + RAD; ++r) m = fmaxf(m, hx[r][col]);
        if (v >= m) {
            int pos = atomicAdd(&cnt, 1);
            if (pos < TCAP) {
                tv[tile_id * TCAP + pos] = v;
                ti[tile_id * TCAP + pos] = (row0 + lr - HALO) * WW + col;
            }
        }
    }
    red[tid] = tmax;
    __syncthreads();
    for (int s = 128; s > 0; s >>= 1) {
        if (tid < s) red[tid] = fmaxf(red[tid], red[tid + s]);
        __syncthreads();
    }
    if (tid == 0) {
        gpart[tile_id]  = red[0];
        tcount[tile_id] = cnt > TCAP ? TCAP : cnt;
    }
}

__device__ __forceinline__ float wm_at_f(float fi, float fj,
                                         const float* qr, const float* qc, const float* qw) {
    float wmv = 0.f;
#pragma unroll
    for (int k = 0; k < KTOP; ++k) {
        float dr = fi - qr[k];
        float dc = fj - qc[k];
        wmv += qw[k] * __expf(-(dr * dr + dc * dc) * 0.02f);
    }
    return wmv;
}

// ---------- K2: redundant per-block select + reweight (+outputs on tile 0) ----------
__global__ void __launch_bounds__(256)
k_fused(const float* __restrict__ hm, const float* __restrict__ fmap,
        const float* __restrict__ gpart, const int* __restrict__ tcount,
        const float* __restrict__ tv, const int* __restrict__ ti,
        float* __restrict__ out_rw, float* __restrict__ out_feats,
        float* __restrict__ out_pos, float* __restrict__ out_probs,
        float* __restrict__ out_valid) {
    int tile = blockIdx.x, b = blockIdx.y, tid = threadIdx.x;
    int row0 = tile * TILE_ROWS;

    __shared__ float cv[CTOT];
    __shared__ int   ci[CTOT];
    __shared__ int   cnt;
    __shared__ int   sct[16];
    __shared__ float red[256];
    __shared__ int   redi[128];
    __shared__ float sel_v[KTOP]; __shared__ int sel_i[KTOP]; __shared__ int sel_p[KTOP];
    __shared__ float s_r[KTOP], s_c[KTOP], s_w[KTOP];
    __shared__ float fc[KTOP][WW];
    __shared__ float sq;

    // ---- threshold from per-tile maxima ----
    if (tid == 0) {
        cnt = 0;
        float g = -INFINITY;
        for (int j = 0; j < 16; ++j) g = fmaxf(g, gpart[b * 16 + j]);
        red[0] = 0.05f * g;
    }
    if (tid < 16) sct[tid] = tcount[b * 16 + tid];
    __syncthreads();
    float thresh = red[0];

    // ---- gather + threshold-filter candidates into LDS ----
    for (int i = tid; i < CTOT; i += 256) {
        int j = i >> 7, p = i & 127;
        if (p < sct[j]) {
            float v = tv[(b * 16 + j) * TCAP + p];
            if (v >= thresh) {
                int pos = atomicAdd(&cnt, 1);
                cv[pos] = v;
                ci[pos] = ti[(b * 16 + j) * TCAP + p];
            }
        }
    }
    __syncthreads();
    int count = cnt;

    // ---- top-8, stable (value desc, index asc) — order-independent of gather ----
    for (int k = 0; k < KTOP; ++k) {
        float bv = -INFINITY; int bi = 0x7fffffff; int bp = -1;
        for (int i = tid; i < count; i += 256) {
            float v = cv[i]; int idx = ci[i];
            if (v > bv || (v == bv && idx < bi)) { bv = v; bi = idx; bp = i; }
        }
        for (int s = 1; s < 64; s <<= 1) {
            float v = __shfl_xor(bv, s); int idx = __shfl_xor(bi, s); int p = __shfl_xor(bp, s);
            if (v > bv || (v == bv && idx < bi)) { bv = v; bi = idx; bp = p; }
        }
        if ((tid & 63) == 0) { int w = tid >> 6; red[w] = bv; redi[w] = bi; redi[64 + w] = bp; }
        __syncthreads();
        if (tid == 0) {
            float v0 = red[0]; int i0 = redi[0]; int p0 = redi[64];
            for (int j = 1; j < 4; ++j)
                if (red[j] > v0 || (red[j] == v0 && redi[j] < i0)) {
                    v0 = red[j]; i0 = redi[j]; p0 = redi[64 + j];
                }
            sel_v[k] = v0; sel_i[k] = i0; sel_p[k] = p0;
            if (p0 >= 0) cv[p0] = -INFINITY;
        }
        __syncthreads();
    }

    // ---- padding + softmax; outputs written by tile-0 block only ----
    if (tid == 0) {
        int next = 0;
        for (int k = 0; k < KTOP; ++k) {
            if (sel_p[k] < 0) {
                for (;;) {
                    bool taken = false;
                    for (int j = 0; j < count; ++j) if (ci[j] == next) { taken = true; break; }
                    if (!taken) break;
                    ++next;
                }
                sel_i[k] = next;
                sel_v[k] = -1.0e9f;
                ++next;
            }
        }
        float m = sel_v[0];
        for (int k = 1; k < KTOP; ++k) m = fmaxf(m, sel_v[k]);
        float e[KTOP], s = 0.f;
        for (int k = 0; k < KTOP; ++k) { e[k] = expf(sel_v[k] - m); s += e[k]; }
        for (int k = 0; k < KTOP; ++k) {
            float prob = e[k] / s;
            int idx = sel_i[k];
            float rrow = (float)(idx / WW);
            float rcol = (float)(idx % WW);
            float vld  = sel_v[k] > -1.0e8f ? 1.f : 0.f;
            if (tile == 0) {
                out_pos[(b * KTOP + k) * 2 + 0] = rrow;
                out_pos[(b * KTOP + k) * 2 + 1] = rcol;
                out_probs[b * KTOP + k] = prob;
                out_valid[b * KTOP + k] = vld;
            }
            s_r[k] = rrow; s_c[k] = rcol; s_w[k] = prob * vld;
        }
    }
    __syncthreads();

    // ---- col factors (concurrent with wmmax scan) ----
    for (int i = tid; i < KTOP * WW; i += 256) {
        int k = i >> 8, col = i & 255;
        float d = (float)col - s_c[k];
        fc[k][col] = __expf(-d * d * 0.02f);
    }

    // ---- analytic weight-map max: argmax within radius 11 of some center ----
    float m = 0.f;
    for (int i = tid; i < KTOP * 529; i += 256) {
        int k = i / 529, o = i - k * 529;
        int rr = (int)s_r[k] + (o / 23) - 11;
        int cc = (int)s_c[k] + (o % 23) - 11;
        if (rr >= 0 && rr < HH && cc >= 0 && cc < WW)
            m = fmaxf(m, wm_at_f((float)rr, (float)cc, s_r, s_c, s_w));
    }
    red[tid] = m;
    __syncthreads();
    for (int s = 128; s > 0; s >>= 1) {
        if (tid < s) red[tid] = fmaxf(red[tid], red[tid + s]);
        __syncthreads();
    }
    if (tid == 0) sq = 0.5f / (red[0] + 1e-8f);
    __syncthreads();
    float inv = sq;

    // ---- feature gather (tile-0 blocks; positions exactly integral -> single tap) ----
    if (tile == 0) {
        for (int t = tid; t < KTOP * NC; t += 256) {
            int k  = t >> 7;
            int ch = t & 127;
            int r = (int)s_r[k];
            int c = (int)s_c[k];
            out_feats[(size_t)b * KTOP * NC + t] = fmap[((size_t)b * NC + ch) * HH * WW + r * WW + c];
        }
    }

    // ---- reweight own tile: separable gaussians, 8 FMA / pixel ----
    int r  = tid >> 4;
    int cb = (tid & 15) * 4;
    float grow = (float)(row0 + r);
    float a[KTOP];
#pragma unroll
    for (int k = 0; k < KTOP; ++k) {
        float d = grow - s_r[k];
        a[k] = s_w[k] * __expf(-d * d * 0.02f);
    }

    const float4* h4 = (const float4*)(hm + (size_t)b * HH * WW + (size_t)(row0 + r) * WW);
    float4*       o4 = (float4*)(out_rw + (size_t)b * HH * WW + (size_t)(row0 + r) * WW);
#pragma unroll
    for (int u = 0; u < 4; ++u) {
        int c4 = cb + u;
        float4 h = h4[c4];
        float4 w = make_float4(0.f, 0.f, 0.f, 0.f);
#pragma unroll
        for (int k = 0; k < KTOP; ++k) {
            float4 f = ((const float4*)&fc[k][0])[c4];
            w.x += a[k] * f.x;
            w.y += a[k] * f.y;
            w.z += a[k] * f.z;
            w.w += a[k] * f.w;
        }
        float4 o;
        o.x = h.x * (0.5f + w.x * inv);
        o.y = h.y * (0.5f + w.y * inv);
        o.z = h.z * (0.5f + w.z * inv);
        o.w = h.w * (0.5f + w.w * inv);
        o4[c4] = o;
    }
}

extern "C" void kernel_launch(void* const* d_in, const int* in_sizes, int n_in,
                              void* d_out, int out_size, void* d_ws, size_t ws_size,
                              hipStream_t stream) {
    const float* heatmap = (const float*)d_in[0];
    const float* fmap    = (const float*)d_in[1];

    float* out = (float*)d_out;
    float* out_reweighted = out;                       // 16*1*256*256 = 1048576
    float* out_feats      = out + 1048576;             // 16*8*128     = 16384
    float* out_pos        = out + 1048576 + 16384;     // 16*8*2       = 256
    float* out_probs      = out_pos + 256;             // 16*8         = 128
    float* out_valid      = out_probs + 128;           // 16*8         = 128

    char* ws = (char*)d_ws;
    float* tv     = (float*)(ws + 0);
    int*   ti     = (int*)  (ws + 131072);
    int*   tcount = (int*)  (ws + 262144);
    float* gpart  = (float*)(ws + 263168);

    k_nms<<<NB * 16, 256, 0, stream>>>(heatmap, gpart, tcount, tv, ti);
    k_fused<<<dim3(16, NB), 256, 0, stream>>>(heatmap, fmap, gpart, tcount, tv, ti,
                                              out_reweighted, out_feats,
                                              out_pos, out_probs, out_valid);
}